// Round 1
// baseline (45.959 us; speedup 1.0000x reference)
//
#include <hip/hip_runtime.h>

// Problem constants (from reference setup_inputs)
#define BB 32
#define NN 16384
#define DK 128
#define DV 128

// out region: [B, N, DV] f32, value = v[b] * Wv[e]   (softmax over size-1 axis == 1)
// attn region: [B, N, 1] f32, value = 1.0f
// d_out = concat(out.flat, attn.flat)

__global__ __launch_bounds__(256) void attn_collapse_kernel(
    const float* __restrict__ v,   // [B]
    const float* __restrict__ Wv,  // [DV]
    float* __restrict__ out,       // [B*N*DV + B*N] floats
    long long total4)              // total float4 count
{
    const long long out4_count = (long long)BB * NN * DV / 4;  // 16,777,216 = b<<19 | rest
    const long long stride = (long long)gridDim.x * blockDim.x;
    for (long long i = (long long)blockIdx.x * blockDim.x + threadIdx.x;
         i < total4; i += stride) {
        float4 val;
        if (i < out4_count) {
            // per-batch float4 count = N*DV/4 = 524288 = 2^19
            int b  = (int)(i >> 19);
            int e4 = (int)(i & 31);             // (i*4) % 128 / 4
            float vb = v[b];
            float4 w = ((const float4*)Wv)[e4];
            val = make_float4(vb * w.x, vb * w.y, vb * w.z, vb * w.w);
        } else {
            val = make_float4(1.0f, 1.0f, 1.0f, 1.0f);
        }
        ((float4*)out)[i] = val;
    }
}

extern "C" void kernel_launch(void* const* d_in, const int* in_sizes, int n_in,
                              void* d_out, int out_size, void* d_ws, size_t ws_size,
                              hipStream_t stream) {
    // setup_inputs order: q, k, v, Wq, Wk, Wv
    const float* v  = (const float*)d_in[2];   // [B,1,1] -> 32 floats
    const float* Wv = (const float*)d_in[5];   // [DV,1]  -> 128 floats
    float* out = (float*)d_out;

    // out_size = B*N*DV + B*N = 67,633,152 floats; divisible by 4.
    long long total4 = (long long)out_size / 4;

    const int block = 256;
    const int grid  = 2048;  // ~8 blocks/CU, grid-stride covers the rest
    attn_collapse_kernel<<<grid, block, 0, stream>>>(v, Wv, out, total4);
}